// Round 2
// baseline (564.608 us; speedup 1.0000x reference)
//
#include <hip/hip_runtime.h>
#include <math.h>

#define NT 16384   // tokens
#define HD 4096    // hidden dim
#define NE 64      // experts
#define TT 64      // tokens per block
#define DC 64      // d-chunk size
#define SX 66      // sX row stride (doubles); 528 B rows, 16B-aligned
#define SL 65      // score matrix stride (doubles)
#define NCH (HD / DC)

__device__ __forceinline__ double dsig(double z) { return 1.0 / (1.0 + exp(-z)); }

// Fused MoE gate, fp64 accumulation (fp32 products are exact in fp64; ordering
// matches the f64 numpy reference so no top-k flips). 256 blocks x 256 threads,
// block tile 64 tokens x 64 experts, thread tile 4x4.
// Thread expert-columns are pairs {2tc,2tc+1,2tc+32,2tc+33} so the sW reads are
// two double2 at 16B stride -> 2-way bank alias (free per m136).
__global__ __launch_bounds__(256) void moe_gate(const float* __restrict__ X,
                                                const float* __restrict__ Wg,
                                                const float* __restrict__ bias,
                                                float* __restrict__ out) {
    __shared__ double sX[DC][SX];   // x chunk, transposed [d][token], fp64
    __shared__ double sW[DC][NE];   // W chunk, natural [d][expert], fp64
    __shared__ double sL[TT][SL];   // sigmoid scores [token][expert], fp64
    __shared__ double sB[NE];       // bias, fp64

    const int tid   = threadIdx.x;
    const int tok0  = blockIdx.x * TT;
    const int tr    = tid >> 4;    // token group: tokens tr*4 .. tr*4+3
    const int tc    = tid & 15;    // expert group: {2tc, 2tc+1, 2tc+32, 2tc+33}
    const int tok_s = tid >> 2;    // staging token 0..63
    const int dv    = tid & 3;     // staging d-vec 0..3

    if (tid < NE) sB[tid] = (double)bias[tid];

    double acc[4][4];
#pragma unroll
    for (int i = 0; i < 4; ++i)
#pragma unroll
        for (int j = 0; j < 4; ++j) acc[i][j] = 0.0;

    const float* xrow = X + (size_t)(tok0 + tok_s) * HD;

    // register prefetch (software pipeline over the 64 d-chunks)
    float4 xr[4], wr[4];
#pragma unroll
    for (int s = 0; s < 4; ++s) {
        xr[s] = *(const float4*)(xrow + s * 16 + dv * 4);
        wr[s] = *(const float4*)(Wg + (size_t)(tid + 256 * s) * 4);
    }

    for (int k = 0; k < NCH; ++k) {
        __syncthreads();   // previous chunk's LDS readers done
#pragma unroll
        for (int s = 0; s < 4; ++s) {
            const int dl = s * 16 + dv * 4;
            sX[dl + 0][tok_s] = (double)xr[s].x;   // transpose + cvt once per element
            sX[dl + 1][tok_s] = (double)xr[s].y;
            sX[dl + 2][tok_s] = (double)xr[s].z;
            sX[dl + 3][tok_s] = (double)xr[s].w;
            const int f = (tid + 256 * s) * 4;     // flat idx into 64x64 W chunk
            const int d = f >> 6, e = f & 63;      // e in {0,4,...,60}
            sW[d][e + 0] = (double)wr[s].x;
            sW[d][e + 1] = (double)wr[s].y;
            sW[d][e + 2] = (double)wr[s].z;
            sW[d][e + 3] = (double)wr[s].w;
        }
        __syncthreads();
        if (k + 1 < NCH) {   // next chunk's global loads hide under ~4096 cyc compute
            const float* xp = xrow + (k + 1) * DC;
            const float* wp = Wg + (size_t)(k + 1) * DC * NE;
#pragma unroll
            for (int s = 0; s < 4; ++s) {
                xr[s] = *(const float4*)(xp + s * 16 + dv * 4);
                wr[s] = *(const float4*)(wp + (size_t)(tid + 256 * s) * 4);
            }
        }
#pragma unroll
        for (int dd = 0; dd < DC; ++dd) {
            const double2 xa = *(const double2*)&sX[dd][tr * 4];      // broadcast
            const double2 xb = *(const double2*)&sX[dd][tr * 4 + 2];
            const double2 wa = *(const double2*)&sW[dd][tc * 2];      // 2-way: free
            const double2 wb = *(const double2*)&sW[dd][tc * 2 + 32];
            acc[0][0] += xa.x * wa.x; acc[0][1] += xa.x * wa.y;
            acc[0][2] += xa.x * wb.x; acc[0][3] += xa.x * wb.y;
            acc[1][0] += xa.y * wa.x; acc[1][1] += xa.y * wa.y;
            acc[1][2] += xa.y * wb.x; acc[1][3] += xa.y * wb.y;
            acc[2][0] += xb.x * wa.x; acc[2][1] += xb.x * wa.y;
            acc[2][2] += xb.x * wb.x; acc[2][3] += xb.x * wb.y;
            acc[3][0] += xb.y * wa.x; acc[3][1] += xb.y * wa.y;
            acc[3][2] += xb.y * wb.x; acc[3][3] += xb.y * wb.y;
        }
    }

    // epilogue: fp64 sigmoid -> LDS score matrix (expert cols 2tc,2tc+1,2tc+32,2tc+33)
    __syncthreads();
    const int e0 = tc * 2, e2 = tc * 2 + 32;
#pragma unroll
    for (int i = 0; i < 4; ++i) {
        const int t = tr * 4 + i;
        sL[t][e0 + 0] = dsig(acc[i][0]);
        sL[t][e0 + 1] = dsig(acc[i][1]);
        sL[t][e2 + 0] = dsig(acc[i][2]);
        sL[t][e2 + 1] = dsig(acc[i][3]);
    }
    __syncthreads();

    // one lane per token: branchless bubble-insert top-8 on fp64 biased scores.
    // Strict '>' with ascending e == lowest-index tie-break (matches top_k).
    if (tid < TT) {
        const int t = tid;
        double bsc[8];
        int    bix[8];
#pragma unroll
        for (int r = 0; r < 8; ++r) { bsc[r] = -INFINITY; bix[r] = 0; }
        for (int e = 0; e < NE; ++e) {
            double cb = sL[t][e] + sB[e];
            int    ci = e;
#pragma unroll
            for (int r = 0; r < 8; ++r) {
                const bool sw = cb > bsc[r];
                const double tb = bsc[r]; const int ti = bix[r];
                bsc[r] = sw ? cb : tb;  bix[r] = sw ? ci : ti;
                cb     = sw ? tb : cb;  ci     = sw ? ti : ci;
            }
        }
        double us[8];
        double sum = 1e-20;
#pragma unroll
        for (int r = 0; r < 8; ++r) { us[r] = sL[t][bix[r]]; sum += us[r]; }

        const size_t o = (size_t)(tok0 + t) * 8;
        float4 i0 = {(float)bix[0], (float)bix[1], (float)bix[2], (float)bix[3]};
        float4 i1 = {(float)bix[4], (float)bix[5], (float)bix[6], (float)bix[7]};
        *(float4*)(out + o)     = i0;
        *(float4*)(out + o + 4) = i1;
        float* ow = out + (size_t)NT * 8;
        const double sc = 2.5 / sum;
        float4 w0 = {(float)(us[0] * sc), (float)(us[1] * sc),
                     (float)(us[2] * sc), (float)(us[3] * sc)};
        float4 w1 = {(float)(us[4] * sc), (float)(us[5] * sc),
                     (float)(us[6] * sc), (float)(us[7] * sc)};
        *(float4*)(ow + o)     = w0;
        *(float4*)(ow + o + 4) = w1;
    }
}

extern "C" void kernel_launch(void* const* d_in, const int* in_sizes, int n_in,
                              void* d_out, int out_size, void* d_ws, size_t ws_size,
                              hipStream_t stream) {
    const float* X  = (const float*)d_in[0];
    const float* Wg = (const float*)d_in[1];
    const float* b  = (const float*)d_in[2];
    float* out = (float*)d_out;
    dim3 grid(NT / TT), block(256);
    hipLaunchKernelGGL(moe_gate, grid, block, 0, stream, X, Wg, b, out);
}